// Round 13
// baseline (32.651 us; speedup 1.0000x reference)
//
#include <hip/hip_runtime.h>

typedef _Float16 f16x8 __attribute__((ext_vector_type(8)));
typedef _Float16 f16x4 __attribute__((ext_vector_type(4)));
typedef float f32x4 __attribute__((ext_vector_type(4)));

#define B_N 8192
#define K_N 256
#define DIM_N 1024

// ---------------- prep_w: U=f16(Dinv-1), W=f16(-2c*Dinv) in MFMA-fragment-PACKED layout ----------------
// pk f16-index: ((cg*32 + kc)*64 + g*16 + cl)*8 + j  where class k=(cg*16+cl), dim d=(kc*32+g*8+j).
// ec[k] = -0.5*(log_det + c2): softmax_k(-0.5*S + ec) == reference resp (row-consts cancel).
__global__ __launch_bounds__(256) void prep_w(const float* __restrict__ Dm,
                                              const float* __restrict__ Cm,
                                              _Float16* __restrict__ Upk,
                                              _Float16* __restrict__ Wpk,
                                              float* __restrict__ ec) {
    const int k = blockIdx.x, t = threadIdx.x;
    const int d = t * 4;
    const float4 dv = *(const float4*)(Dm + (size_t)k * DIM_N + d);
    const float4 cv = *(const float4*)(Cm + (size_t)k * DIM_N + d);
    float dd[4] = {dv.x, dv.y, dv.z, dv.w};
    float cc[4] = {cv.x, cv.y, cv.z, cv.w};
    f16x4 uo, wo;
    float llog = 0.f, lc2 = 0.f;
#pragma unroll
    for (int i = 0; i < 4; ++i) {
        float da = fabsf(dd[i]) + 1e-4f;
        float dinv = 1.0f / da;
        llog += logf(da);
        lc2 += cc[i] * cc[i] * dinv;
        uo[i] = (_Float16)(dinv - 1.0f);
        wo[i] = (_Float16)(-2.0f * cc[i] * dinv);
    }
    const int cg = k >> 4, cl = k & 15;
    const int kc = d >> 5, g = (d >> 3) & 3, j0 = d & 7;
    const size_t off = ((size_t)(cg * 32 + kc) * 64 + g * 16 + cl) * 8 + j0;
    *(f16x4*)(Upk + off) = uo;
    *(f16x4*)(Wpk + off) = wo;
    float both = llog + lc2;
#pragma unroll
    for (int m = 1; m <= 32; m <<= 1) both += __shfl_xor(both, m, 64);
    __shared__ float sb[4];
    if ((t & 63) == 0) sb[t >> 6] = both;
    __syncthreads();
    if (t == 0) ec[k] = -0.5f * (sb[0] + sb[1] + sb[2] + sb[3]);
}

// ---------------- gmm_gemm: 64 rows x 128 classes per block (halves B L2 traffic vs BN=256) ----------------
// grid 256 = 128 rowp x 2 colp (colp = bid>>7: a rowp's two col-blocks share an XCD -> x panel L2 hit).
// 8 waves (512 thr): wr = wave>>2 (2), wc = wave&3 (4); wave-tile 32 rows x 32 classes (m2 n2, 2 products).
// A: fragment-packed LDS (conflict-free stride-1 frag reads), quarters of 256 dims, double-buffered
// (2 x 32KB), 4 barriers total; x^2 computed in-register. B: packed-array register stream, 2 banks.
__global__ __launch_bounds__(512, 1)
void gmm_gemm(const float* __restrict__ x,
              const _Float16* __restrict__ Upk,
              const _Float16* __restrict__ Wpk,
              float* __restrict__ S) {
    __shared__ __align__(16) char xlds[65536];  // 2 bufs x (4 chunks x 8 frags x 1KB)

    const int tid = threadIdx.x;
    const int wave = tid >> 6, lane = tid & 63;
    const int l15 = lane & 15, g4 = lane >> 4;
    const int wr = wave >> 2, wc = wave & 3;
    const int bid = blockIdx.x;
    const int rowp = bid & 127, colp = bid >> 7;
    const int bRow = rowp * 64, bCol = colp * 128;

    // staging: thread -> row r = tid>>3 (0..63); 32 dims: d(j) = (tid&7)*4 + j*32, j=0..7 (coalesced per j)
    const int sr = tid >> 3, q4 = tid & 7;
    const float* xq = x + (size_t)(bRow + sr) * DIM_N + q4 * 4;
    // fragment-packed write offsets: j -> chunk cl=j>>1, k2=j&1; addr in quarter tile
    int wAddr[8];
#pragma unroll
    for (int j = 0; j < 8; ++j) {
        const int cl = j >> 1, k2 = j & 1;
        const int fi = (sr >> 4) * 2 + k2;
        wAddr[j] = cl * 8192 + fi * 1024 + ((sr & 15) + 16 * (q4 >> 1)) * 16 + (q4 & 1) * 8;
    }

    // B packed bases: wave's class-groups cg = colp*8 + wc*2 + n
    const _Float16* upb = Upk + (size_t)(colp * 8 + wc * 2) * 32 * 512 + lane * 8;
    const _Float16* wpb = Wpk + (size_t)(colp * 8 + wc * 2) * 32 * 512 + lane * 8;

    f32x4 acc[2][2];
#pragma unroll
    for (int m = 0; m < 2; ++m)
#pragma unroll
        for (int n = 0; n < 2; ++n) { f32x4 z = {0.f, 0.f, 0.f, 0.f}; acc[m][n] = z; }

    float4 xs[2][8];           // 2 staging banks x 8 float4 (32 dims)
    f16x8 ub[2][2][2], wb[2][2][2];  // [bank][n][k2]

    auto issueQ = [&](int bank, int q) {
#pragma unroll
        for (int j = 0; j < 8; ++j) xs[bank][j] = *(const float4*)(xq + q * 256 + j * 32);
    };
    auto writeQ = [&](int bank, int buf) {
        char* base = xlds + buf * 32768;
#pragma unroll
        for (int j = 0; j < 8; ++j) {
            const float4 v = xs[bank][j];
            f16x4 h = {(_Float16)v.x, (_Float16)v.y, (_Float16)v.z, (_Float16)v.w};
            *(f16x4*)(base + wAddr[j]) = h;
        }
    };
    auto issueB = [&](int bank, int c) {
#pragma unroll
        for (int n = 0; n < 2; ++n)
#pragma unroll
            for (int k2 = 0; k2 < 2; ++k2) {
                const int kc = c * 2 + k2;
                ub[bank][n][k2] = *(const f16x8*)(upb + (size_t)(n * 32 + kc) * 512);
                wb[bank][n][k2] = *(const f16x8*)(wpb + (size_t)(n * 32 + kc) * 512);
            }
    };
    auto compute = [&](int c, int bank) {
        const char* base = xlds + ((c >> 2) & 1) * 32768 + (c & 3) * 8192;
        f16x8 axf[2][2];
#pragma unroll
        for (int m = 0; m < 2; ++m)
#pragma unroll
            for (int k2 = 0; k2 < 2; ++k2) {
                const int fi = (wr * 2 + m) * 2 + k2;
                axf[m][k2] = *(const f16x8*)(base + fi * 1024 + lane * 16);
            }
#pragma unroll
        for (int m = 0; m < 2; ++m)
#pragma unroll
            for (int k2 = 0; k2 < 2; ++k2) {
                const f16x8 a2 = axf[m][k2] * axf[m][k2];   // x^2 in-register
#pragma unroll
                for (int n = 0; n < 2; ++n) {
                    acc[m][n] = __builtin_amdgcn_mfma_f32_16x16x32_f16(a2, ub[bank][n][k2], acc[m][n], 0, 0, 0);
                    acc[m][n] = __builtin_amdgcn_mfma_f32_16x16x32_f16(axf[m][k2], wb[bank][n][k2], acc[m][n], 0, 0, 0);
                }
            }
    };

    // ---- prologue ----
    issueB(0, 0); issueB(1, 1);
    issueQ(0, 0); issueQ(1, 1);
    writeQ(0, 0);
    asm volatile("s_waitcnt lgkmcnt(0)" ::: "memory");
    __builtin_amdgcn_s_barrier();              // quarter 0 ready (buf 0)
    __builtin_amdgcn_sched_barrier(0);
    writeQ(1, 1);                              // stage quarter 1 -> buf 1
    issueQ(0, 2);
    compute(0, 0);  issueB(0, 2);
    compute(1, 1);  issueB(1, 3);
    compute(2, 0);  issueB(0, 4);
    compute(3, 1);  issueB(1, 5);
    asm volatile("s_waitcnt lgkmcnt(0)" ::: "memory");
    __builtin_amdgcn_s_barrier();              // quarter 1 ready; buf0 free
    __builtin_amdgcn_sched_barrier(0);
    writeQ(0, 0);                              // stage quarter 2 -> buf 0
    issueQ(1, 3);
    compute(4, 0);  issueB(0, 6);
    compute(5, 1);  issueB(1, 7);
    compute(6, 0);  issueB(0, 8);
    compute(7, 1);  issueB(1, 9);
    asm volatile("s_waitcnt lgkmcnt(0)" ::: "memory");
    __builtin_amdgcn_s_barrier();              // quarter 2 ready; buf1 free
    __builtin_amdgcn_sched_barrier(0);
    writeQ(1, 1);                              // stage quarter 3 -> buf 1
    compute(8, 0);   issueB(0, 10);
    compute(9, 1);   issueB(1, 11);
    compute(10, 0);  issueB(0, 12);
    compute(11, 1);  issueB(1, 13);
    asm volatile("s_waitcnt lgkmcnt(0)" ::: "memory");
    __builtin_amdgcn_s_barrier();              // quarter 3 ready
    __builtin_amdgcn_sched_barrier(0);
    compute(12, 0);  issueB(0, 14);
    compute(13, 1);  issueB(1, 15);
    compute(14, 0);
    compute(15, 1);

    // ---- epilogue: raw scores (dist_sq - c2 - row_const) -> S ----
#pragma unroll
    for (int m = 0; m < 2; ++m) {
        const int rb = bRow + wr * 32 + m * 16 + g4 * 4;
        const int cb = bCol + wc * 32 + l15;
#pragma unroll
        for (int j = 0; j < 4; ++j) {
            float* p = S + (size_t)(rb + j) * K_N + cb;
            p[0] = acc[m][0][j];
            p[16] = acc[m][1][j];
        }
    }
}

// ---------------- gmm_soft: out = softmax_k(-0.5*S + ec[k]) per row, in place ----------------
__global__ __launch_bounds__(256)
void gmm_soft(float* __restrict__ S, const float* __restrict__ ecg) {
    const int tid = threadIdx.x;
    const int wave = tid >> 6, lane = tid & 63;
    const int r = blockIdx.x * 4 + wave;
    const int k0 = lane * 4;
    float4 s = *(const float4*)(S + (size_t)r * K_N + k0);
    float4 cv = *(const float4*)(ecg + k0);
    float e[4] = {fmaf(-0.5f, s.x, cv.x), fmaf(-0.5f, s.y, cv.y),
                  fmaf(-0.5f, s.z, cv.z), fmaf(-0.5f, s.w, cv.w)};
    float m = fmaxf(fmaxf(e[0], e[1]), fmaxf(e[2], e[3]));
#pragma unroll
    for (int msk = 1; msk <= 32; msk <<= 1) m = fmaxf(m, __shfl_xor(m, msk, 64));
    float p[4], sum = 0.f;
#pragma unroll
    for (int j = 0; j < 4; ++j) {
        p[j] = __expf(e[j] - m);
        sum += p[j];
    }
#pragma unroll
    for (int msk = 1; msk <= 32; msk <<= 1) sum += __shfl_xor(sum, msk, 64);
    const float inv = 1.0f / sum;
    *(float4*)(S + (size_t)r * K_N + k0) = make_float4(p[0] * inv, p[1] * inv, p[2] * inv, p[3] * inv);
}

extern "C" void kernel_launch(void* const* d_in, const int* in_sizes, int n_in,
                              void* d_out, int out_size, void* d_ws, size_t ws_size,
                              hipStream_t stream) {
    const float* x = (const float*)d_in[0];
    const float* cen = (const float*)d_in[1];
    const float* Dm = (const float*)d_in[2];
    float* out = (float*)d_out;

    char* ws = (char*)d_ws;
    _Float16* Upk = (_Float16*)(ws);                // 512 KB packed
    _Float16* Wpk = (_Float16*)(ws + 524288);       // 512 KB packed
    float* ec = (float*)(ws + 1048576);             // 1 KB

    prep_w<<<dim3(K_N), dim3(256), 0, stream>>>(Dm, cen, Upk, Wpk, ec);
    gmm_gemm<<<dim3(256), dim3(512), 0, stream>>>(x, Upk, Wpk, out);
    gmm_soft<<<dim3(B_N / 4), dim3(256), 0, stream>>>(out, ec);
}